// Round 5
// baseline (316.678 us; speedup 1.0000x reference)
//
#include <hip/hip_runtime.h>
#include <stdint.h>

#define B_ROWS 8192
#define I_DIM  1024
#define N_DIM  1024
#define NDEG   9                  // D+1 (d = 0..8)
#define K_DIM  (I_DIM * (NDEG-1)) // 8192; k = (d-1)*1024 + i, d = 1..8 (d=0 folded into bias)

typedef __attribute__((ext_vector_type(8)))  short short8;
typedef __attribute__((ext_vector_type(16))) float f32x16;

__device__ __forceinline__ unsigned short f2bf(float f) {
  union { float f; uint32_t u; } v; v.f = f;
  uint32_t u = v.u;
  u += 0x7FFFu + ((u >> 16) & 1u);   // round-to-nearest-even
  return (unsigned short)(u >> 16);
}

__device__ __forceinline__ float bf2f(unsigned short h) {
  union { uint32_t u; float f; } v; v.u = ((uint32_t)h) << 16;
  return v.f;
}

// ---------------- basis: x[b,i] -> A[b, (d-1)*1024+i] = T_d(clip(tanh(x))), d=1..8 ----------
__global__ __launch_bounds__(256) void basis_kernel(const float* __restrict__ x,
                                                    unsigned short* __restrict__ A) {
  const int b  = blockIdx.x;
  const int i0 = threadIdx.x * 4;
  const float4 xv = *reinterpret_cast<const float4*>(x + (size_t)b * I_DIM + i0);
  float t[4];
  t[0] = fminf(fmaxf(tanhf(xv.x), -0.999f), 0.999f);
  t[1] = fminf(fmaxf(tanhf(xv.y), -0.999f), 0.999f);
  t[2] = fminf(fmaxf(tanhf(xv.z), -0.999f), 0.999f);
  t[3] = fminf(fmaxf(tanhf(xv.w), -0.999f), 0.999f);

  unsigned short* outb = A + (size_t)b * K_DIM + i0;
  float Tp[4] = {1.f, 1.f, 1.f, 1.f};
  float Tc[4] = {t[0], t[1], t[2], t[3]};
  #pragma unroll
  for (int d = 1; d < NDEG; ++d) {
    ushort4 o4;
    o4.x = f2bf(Tc[0]); o4.y = f2bf(Tc[1]); o4.z = f2bf(Tc[2]); o4.w = f2bf(Tc[3]);
    *reinterpret_cast<ushort4*>(outb + (size_t)(d - 1) * I_DIM) = o4;
    if (d < NDEG - 1) {
      #pragma unroll
      for (int j = 0; j < 4; ++j) {
        float Tn = 2.0f * t[j] * Tc[j] - Tp[j];
        Tp[j] = Tc[j]; Tc[j] = Tn;
      }
    }
  }
}

// ---------------- repack: C[i,o,d] fp32 -> Bt[o,(d-1)*1024+i] bf16 (d>=1), bias[o] += sum_i C[i,o,0]
__global__ __launch_bounds__(256) void repack_kernel(const float* __restrict__ cf,
                                                     unsigned short* __restrict__ Bt,
                                                     float* __restrict__ bias) {
  __shared__ unsigned short L[32][584];   // [i_local][o_local*9+d], padded
  const int i0  = blockIdx.x * 32;
  const int o0  = blockIdx.y * 64;
  const int tid = threadIdx.x;

  #pragma unroll
  for (int j = 0; j < 18; ++j) {                 // 18*256 = 4608 float4 = 32*576 floats
    const int f4  = j * 256 + tid;
    const int il  = f4 / 144;
    const int odq = f4 % 144;
    const float4 v = *reinterpret_cast<const float4*>(
        cf + ((size_t)(i0 + il) * N_DIM + o0) * NDEG + (size_t)odq * 4);
    ushort4 w;
    w.x = f2bf(v.x); w.y = f2bf(v.y); w.z = f2bf(v.z); w.w = f2bf(v.w);
    *reinterpret_cast<ushort4*>(&L[il][odq * 4]) = w;
  }
  __syncthreads();

  for (int od = tid; od < 576; od += 256) {      // od = o_local*9 + d
    const int o = od / 9, d = od % 9;
    if (d == 0) {
      float s = 0.f;
      #pragma unroll
      for (int il = 0; il < 32; ++il) s += bf2f(L[il][od]);
      atomicAdd(&bias[o0 + o], s);
    } else {
      const size_t base = (size_t)(o0 + o) * K_DIM + (size_t)(d - 1) * I_DIM + i0;
      #pragma unroll
      for (int ci = 0; ci < 4; ++ci) {           // 4 x 8 consecutive i = 64B line
        uint32_t uu[4];
        #pragma unroll
        for (int p = 0; p < 4; ++p) {
          unsigned short lo = L[ci * 8 + p * 2 + 0][od];
          unsigned short hi = L[ci * 8 + p * 2 + 1][od];
          uu[p] = (uint32_t)lo | ((uint32_t)hi << 16);
        }
        uint4 u; u.x = uu[0]; u.y = uu[1]; u.z = uu[2]; u.w = uu[3];
        *reinterpret_cast<uint4*>(Bt + base + ci * 8) = u;
      }
    }
  }
}

// ---------------- GEMM: C[m,n] = bias[n] + sum_k A[m,k]*Bt[n,k], bf16 in / fp32 out ---------
// 128x128 tile, 2 waves (128 threads). Wave tile = 128x64 (4x2 of 32x32x16 MFMA):
// per ks-step 6 ds_read_b128 feed 8 MFMAs (LDS read redundancy 1.5x vs 2x with 4 waves).
// grid (x=m,y=n) keeps the XCD A-slab swizzle. Reads interleaved per-ks (round-3 pattern).
__global__ __launch_bounds__(128, 2) void gemm_kernel(const unsigned short* __restrict__ A,
                                                      const unsigned short* __restrict__ Bt,
                                                      const float* __restrict__ bias,
                                                      float* __restrict__ C) {
  __shared__ unsigned short As[128 * 64];
  __shared__ unsigned short Bs[128 * 64];
  const int tid  = threadIdx.x;
  const int lane = tid & 63;
  const int wn   = tid >> 6;        // wave 0 -> n 0..63, wave 1 -> n 64..127
  const int l31  = lane & 31;
  const int half = lane >> 5;       // k-offset 8*half within 16-wide k-step
  const int m0   = blockIdx.x * 128;
  const int n0   = blockIdx.y * 128;

  const int sr   = tid >> 3;        // 0..15 (staging row within issue group)
  const int slot = tid & 7;         // 16B chunk slot within 128B row

  f32x16 acc[4][2];
  #pragma unroll
  for (int a = 0; a < 4; ++a)
    #pragma unroll
    for (int b = 0; b < 2; ++b)
      #pragma unroll
      for (int r = 0; r < 16; ++r)
        acc[a][b][r] = 0.f;

  for (int kt = 0; kt < K_DIM / 64; ++kt) {
    const int k0 = kt * 64;
    #pragma unroll
    for (int s = 0; s < 8; ++s) {
      const int r  = s * 16 + sr;
      const int gc = slot ^ (r & 7);    // swizzle global side; LDS side stays lane*16
      const unsigned short* srcA = A + (size_t)(m0 + r) * K_DIM + k0 + gc * 8;
      __builtin_amdgcn_global_load_lds(
          (const __attribute__((address_space(1))) void*)srcA,
          (__attribute__((address_space(3))) void*)&As[r * 64 + slot * 8], 16, 0, 0);
      const unsigned short* srcB = Bt + (size_t)(n0 + r) * K_DIM + k0 + gc * 8;
      __builtin_amdgcn_global_load_lds(
          (const __attribute__((address_space(1))) void*)srcB,
          (__attribute__((address_space(3))) void*)&Bs[r * 64 + slot * 8], 16, 0, 0);
    }
    __syncthreads();

    #pragma unroll
    for (int ks = 0; ks < 4; ++ks) {
      short8 av[4], bv[2];
      #pragma unroll
      for (int mi = 0; mi < 4; ++mi) {
        const int row = mi * 32 + l31;
        const int sl  = (ks * 2 + half) ^ (row & 7);
        av[mi] = *reinterpret_cast<const short8*>(&As[row * 64 + sl * 8]);
      }
      #pragma unroll
      for (int ni = 0; ni < 2; ++ni) {
        const int row = wn * 64 + ni * 32 + l31;
        const int sl  = (ks * 2 + half) ^ (row & 7);
        bv[ni] = *reinterpret_cast<const short8*>(&Bs[row * 64 + sl * 8]);
      }
      #pragma unroll
      for (int mi = 0; mi < 4; ++mi)
        #pragma unroll
        for (int ni = 0; ni < 2; ++ni)
          acc[mi][ni] = __builtin_amdgcn_mfma_f32_32x32x16_bf16(av[mi], bv[ni],
                                                                acc[mi][ni], 0, 0, 0);
    }
    __syncthreads();
  }

  // epilogue: 32x32 C/D layout col = lane&31, row = (reg&3) + 8*(reg>>2) + 4*(lane>>5)
  #pragma unroll
  for (int ni = 0; ni < 2; ++ni) {
    const int col  = n0 + wn * 64 + ni * 32 + l31;
    const float bc = bias[col];
    #pragma unroll
    for (int mi = 0; mi < 4; ++mi) {
      const int rbase = m0 + mi * 32 + 4 * half;
      #pragma unroll
      for (int r = 0; r < 16; ++r) {
        const int row = rbase + (r & 3) + 8 * (r >> 2);
        C[(size_t)row * N_DIM + col] = acc[mi][ni][r] + bc;
      }
    }
  }
}

extern "C" void kernel_launch(void* const* d_in, const int* in_sizes, int n_in,
                              void* d_out, int out_size, void* d_ws, size_t ws_size,
                              hipStream_t stream) {
  const float* x      = (const float*)d_in[0];
  const float* coeffs = (const float*)d_in[1];
  float* y            = (float*)d_out;

  const size_t bt_bytes = (size_t)N_DIM * K_DIM * sizeof(unsigned short); // 16.78 MB
  unsigned short* Bt = (unsigned short*)d_ws;
  float* bias        = (float*)((char*)d_ws + bt_bytes);
  unsigned short* A  = (unsigned short*)((char*)d_ws + bt_bytes + 4096);

  // bias accumulator must start at zero (ws is poisoned 0xAA each call)
  hipMemsetAsync(bias, 0, N_DIM * sizeof(float), stream);

  // coeff repack + bias reduction
  repack_kernel<<<dim3(I_DIM / 32, N_DIM / 64), 256, 0, stream>>>(coeffs, Bt, bias);

  // chunk M so (Bt + bias + A-chunk) fits in workspace; full A is ~134 MB
  size_t avail    = (ws_size > bt_bytes + 4096) ? (ws_size - bt_bytes - 4096) : 0;
  size_t rows_fit = avail / ((size_t)K_DIM * sizeof(unsigned short));
  int m_chunk = (int)((rows_fit / 128) * 128);
  if (m_chunk > B_ROWS) m_chunk = B_ROWS;
  if (m_chunk < 128)    m_chunk = 128;

  for (int m0 = 0; m0 < B_ROWS; m0 += m_chunk) {
    int mc = B_ROWS - m0; if (mc > m_chunk) mc = m_chunk;
    basis_kernel<<<mc, 256, 0, stream>>>(x + (size_t)m0 * I_DIM, A);
    gemm_kernel<<<dim3(mc / 128, N_DIM / 128), 128, 0, stream>>>(
        A, Bt, bias, y + (size_t)m0 * N_DIM);
  }
}

// Round 6
// 273.944 us; speedup vs baseline: 1.1560x; 1.1560x over previous
//
#include <hip/hip_runtime.h>
#include <stdint.h>

#define B_ROWS 8192
#define I_DIM  1024
#define N_DIM  1024
#define NDEG   9                  // D+1 (d = 0..8)
#define K_DIM  (I_DIM * (NDEG-1)) // 8192; k = (d-1)*1024 + i, d = 1..8 (d=0 folded into bias)

typedef __attribute__((ext_vector_type(8)))  short short8;
typedef __attribute__((ext_vector_type(16))) float f32x16;

__device__ __forceinline__ unsigned short f2bf(float f) {
  union { float f; uint32_t u; } v; v.f = f;
  uint32_t u = v.u;
  u += 0x7FFFu + ((u >> 16) & 1u);   // round-to-nearest-even
  return (unsigned short)(u >> 16);
}

__device__ __forceinline__ float bf2f(unsigned short h) {
  union { uint32_t u; float f; } v; v.u = ((uint32_t)h) << 16;
  return v.f;
}

// row-hash for LDS chunk swizzle: includes row bit4 so rows r and r+16 (which the
// 32x32 MFMA fragment reads at the SAME k-chunk within one lane quad-group
// {i,i+16,i+32,i+48}) land in different bank groups. h(r) = (r&7) ^ (bit4(r)<<2).
__device__ __forceinline__ int rowhash(int r) {
  return (r & 7) ^ ((r >> 2) & 4);
}

// ---------------- basis: x[b,i] -> A[b, (d-1)*1024+i] = T_d(clip(tanh(x))), d=1..8 ----------
__global__ __launch_bounds__(256) void basis_kernel(const float* __restrict__ x,
                                                    unsigned short* __restrict__ A) {
  const int b  = blockIdx.x;
  const int i0 = threadIdx.x * 4;
  const float4 xv = *reinterpret_cast<const float4*>(x + (size_t)b * I_DIM + i0);
  float t[4];
  t[0] = fminf(fmaxf(tanhf(xv.x), -0.999f), 0.999f);
  t[1] = fminf(fmaxf(tanhf(xv.y), -0.999f), 0.999f);
  t[2] = fminf(fmaxf(tanhf(xv.z), -0.999f), 0.999f);
  t[3] = fminf(fmaxf(tanhf(xv.w), -0.999f), 0.999f);

  unsigned short* outb = A + (size_t)b * K_DIM + i0;
  float Tp[4] = {1.f, 1.f, 1.f, 1.f};
  float Tc[4] = {t[0], t[1], t[2], t[3]};
  #pragma unroll
  for (int d = 1; d < NDEG; ++d) {
    ushort4 o4;
    o4.x = f2bf(Tc[0]); o4.y = f2bf(Tc[1]); o4.z = f2bf(Tc[2]); o4.w = f2bf(Tc[3]);
    *reinterpret_cast<ushort4*>(outb + (size_t)(d - 1) * I_DIM) = o4;
    if (d < NDEG - 1) {
      #pragma unroll
      for (int j = 0; j < 4; ++j) {
        float Tn = 2.0f * t[j] * Tc[j] - Tp[j];
        Tp[j] = Tc[j]; Tc[j] = Tn;
      }
    }
  }
}

// ---------------- repack: C[i,o,d] fp32 -> Bt[o,(d-1)*1024+i] bf16 (d>=1), bias[o] += sum_i C[i,o,0]
__global__ __launch_bounds__(256) void repack_kernel(const float* __restrict__ cf,
                                                     unsigned short* __restrict__ Bt,
                                                     float* __restrict__ bias) {
  __shared__ unsigned short L[32][584];   // [i_local][o_local*9+d], padded
  const int i0  = blockIdx.x * 32;
  const int o0  = blockIdx.y * 64;
  const int tid = threadIdx.x;

  #pragma unroll
  for (int j = 0; j < 18; ++j) {                 // 18*256 = 4608 float4 = 32*576 floats
    const int f4  = j * 256 + tid;
    const int il  = f4 / 144;
    const int odq = f4 % 144;
    const float4 v = *reinterpret_cast<const float4*>(
        cf + ((size_t)(i0 + il) * N_DIM + o0) * NDEG + (size_t)odq * 4);
    ushort4 w;
    w.x = f2bf(v.x); w.y = f2bf(v.y); w.z = f2bf(v.z); w.w = f2bf(v.w);
    *reinterpret_cast<ushort4*>(&L[il][odq * 4]) = w;
  }
  __syncthreads();

  for (int od = tid; od < 576; od += 256) {      // od = o_local*9 + d
    const int o = od / 9, d = od % 9;
    if (d == 0) {
      float s = 0.f;
      #pragma unroll
      for (int il = 0; il < 32; ++il) s += bf2f(L[il][od]);
      atomicAdd(&bias[o0 + o], s);
    } else {
      const size_t base = (size_t)(o0 + o) * K_DIM + (size_t)(d - 1) * I_DIM + i0;
      #pragma unroll
      for (int ci = 0; ci < 4; ++ci) {           // 4 x 8 consecutive i = 64B line
        uint32_t uu[4];
        #pragma unroll
        for (int p = 0; p < 4; ++p) {
          unsigned short lo = L[ci * 8 + p * 2 + 0][od];
          unsigned short hi = L[ci * 8 + p * 2 + 1][od];
          uu[p] = (uint32_t)lo | ((uint32_t)hi << 16);
        }
        uint4 u; u.x = uu[0]; u.y = uu[1]; u.z = uu[2]; u.w = uu[3];
        *reinterpret_cast<uint4*>(Bt + base + ci * 8) = u;
      }
    }
  }
}

// ---------------- GEMM: C[m,n] = bias[n] + sum_k A[m,k]*Bt[n,k], bf16 in / fp32 out ---------
// grid = (x = m-tile [64], y = n-tile [8]): XCD-swizzled so the 8 n-tiles sharing an A-slab
// land on the same XCD. Inner tile: 2x2 x mfma_f32_32x32x16_bf16 per wave; LDS chunk
// swizzle uses rowhash() (incl. row bit4) -> conflict-free for the 32x32 fragment pattern.
__global__ __launch_bounds__(256) void gemm_kernel(const unsigned short* __restrict__ A,
                                                   const unsigned short* __restrict__ Bt,
                                                   const float* __restrict__ bias,
                                                   float* __restrict__ C) {
  __shared__ unsigned short As[128 * 64];
  __shared__ unsigned short Bs[128 * 64];
  const int tid  = threadIdx.x;
  const int lane = tid & 63;
  const int wave = tid >> 6;
  const int l31  = lane & 31;
  const int half = lane >> 5;       // 0..1 -> k-offset 8*half
  const int wm   = wave >> 1;       // 0..1
  const int wn   = wave & 1;        // 0..1
  const int m0   = blockIdx.x * 128;
  const int n0   = blockIdx.y * 128;

  const int sr   = tid >> 3;        // 0..31 (staging row within issue group)
  const int slot = tid & 7;         // 16B chunk slot within 128B row

  f32x16 acc[2][2];
  #pragma unroll
  for (int a = 0; a < 2; ++a)
    #pragma unroll
    for (int b = 0; b < 2; ++b)
      #pragma unroll
      for (int r = 0; r < 16; ++r)
        acc[a][b][r] = 0.f;

  for (int kt = 0; kt < K_DIM / 64; ++kt) {
    const int k0 = kt * 64;
    #pragma unroll
    for (int s = 0; s < 4; ++s) {
      const int r  = s * 32 + sr;
      const int gc = slot ^ rowhash(r);   // swizzle global side; LDS side stays lane*16
      const unsigned short* srcA = A + (size_t)(m0 + r) * K_DIM + k0 + gc * 8;
      __builtin_amdgcn_global_load_lds(
          (const __attribute__((address_space(1))) void*)srcA,
          (__attribute__((address_space(3))) void*)&As[r * 64 + slot * 8], 16, 0, 0);
      const unsigned short* srcB = Bt + (size_t)(n0 + r) * K_DIM + k0 + gc * 8;
      __builtin_amdgcn_global_load_lds(
          (const __attribute__((address_space(1))) void*)srcB,
          (__attribute__((address_space(3))) void*)&Bs[r * 64 + slot * 8], 16, 0, 0);
    }
    __syncthreads();

    // 4 k-steps of 16; A-frag: lane holds A[row][k = ks*16 + half*8 + j]
    short8 av[2][4], bv[2][4];
    #pragma unroll
    for (int mi = 0; mi < 2; ++mi) {
      const int row = wm * 64 + mi * 32 + l31;
      #pragma unroll
      for (int ks = 0; ks < 4; ++ks) {
        const int c  = ks * 2 + half;          // 16B chunk index 0..7
        const int sl = c ^ rowhash(row);
        av[mi][ks] = *reinterpret_cast<const short8*>(&As[row * 64 + sl * 8]);
      }
    }
    #pragma unroll
    for (int ni = 0; ni < 2; ++ni) {
      const int row = wn * 64 + ni * 32 + l31;
      #pragma unroll
      for (int ks = 0; ks < 4; ++ks) {
        const int c  = ks * 2 + half;
        const int sl = c ^ rowhash(row);
        bv[ni][ks] = *reinterpret_cast<const short8*>(&Bs[row * 64 + sl * 8]);
      }
    }
    #pragma unroll
    for (int ks = 0; ks < 4; ++ks)
      #pragma unroll
      for (int mi = 0; mi < 2; ++mi)
        #pragma unroll
        for (int ni = 0; ni < 2; ++ni)
          acc[mi][ni] = __builtin_amdgcn_mfma_f32_32x32x16_bf16(av[mi][ks], bv[ni][ks],
                                                                acc[mi][ni], 0, 0, 0);
    __syncthreads();
  }

  // epilogue: 32x32 C/D layout col = lane&31, row = (reg&3) + 8*(reg>>2) + 4*(lane>>5)
  #pragma unroll
  for (int ni = 0; ni < 2; ++ni) {
    const int col  = n0 + wn * 64 + ni * 32 + l31;
    const float bc = bias[col];
    #pragma unroll
    for (int mi = 0; mi < 2; ++mi) {
      const int rbase = m0 + wm * 64 + mi * 32 + 4 * half;
      #pragma unroll
      for (int r = 0; r < 16; ++r) {
        const int row = rbase + (r & 3) + 8 * (r >> 2);
        C[(size_t)row * N_DIM + col] = acc[mi][ni][r] + bc;
      }
    }
  }
}

extern "C" void kernel_launch(void* const* d_in, const int* in_sizes, int n_in,
                              void* d_out, int out_size, void* d_ws, size_t ws_size,
                              hipStream_t stream) {
  const float* x      = (const float*)d_in[0];
  const float* coeffs = (const float*)d_in[1];
  float* y            = (float*)d_out;

  const size_t bt_bytes = (size_t)N_DIM * K_DIM * sizeof(unsigned short); // 16.78 MB
  unsigned short* Bt = (unsigned short*)d_ws;
  float* bias        = (float*)((char*)d_ws + bt_bytes);
  unsigned short* A  = (unsigned short*)((char*)d_ws + bt_bytes + 4096);

  // bias accumulator must start at zero (ws is poisoned 0xAA each call)
  hipMemsetAsync(bias, 0, N_DIM * sizeof(float), stream);

  // coeff repack + bias reduction
  repack_kernel<<<dim3(I_DIM / 32, N_DIM / 64), 256, 0, stream>>>(coeffs, Bt, bias);

  // chunk M so (Bt + bias + A-chunk) fits in workspace; full A is ~134 MB
  size_t avail    = (ws_size > bt_bytes + 4096) ? (ws_size - bt_bytes - 4096) : 0;
  size_t rows_fit = avail / ((size_t)K_DIM * sizeof(unsigned short));
  int m_chunk = (int)((rows_fit / 128) * 128);
  if (m_chunk > B_ROWS) m_chunk = B_ROWS;
  if (m_chunk < 128)    m_chunk = 128;

  for (int m0 = 0; m0 < B_ROWS; m0 += m_chunk) {
    int mc = B_ROWS - m0; if (mc > m_chunk) mc = m_chunk;
    basis_kernel<<<mc, 256, 0, stream>>>(x + (size_t)m0 * I_DIM, A);
    gemm_kernel<<<dim3(mc / 128, N_DIM / 128), 256, 0, stream>>>(
        A, Bt, bias, y + (size_t)m0 * N_DIM);
  }
}